// Round 11
// baseline (256.691 us; speedup 1.0000x reference)
//
#include <hip/hip_runtime.h>
#include <hip/hip_fp16.h>

#define IN_CH 16
#define OUT_CH 8

#define NT 256          // threads per block
#define EPT 24          // edges per thread in k_bin
#define TILE (NT*EPT)   // 6144 edges per tile
#define NBUK 512        // allocated buckets (489 active for N=500k)
#define BSHIFT 10       // bucket = dst >> 10  (1024 nodes per bucket)
#define BNODES 1024
#define BMASK 1023
#define SRCBITS 19      // src < 2^19 (N=500000 < 524288)
#define SRCMASK 0x7FFFF
#define CAP 11264       // slots per bucket (mean 10240, +10 sigma); CAP/NT == 44
#define RPT 44          // register-cached edges per thread in k_sort

typedef float __attribute__((ext_vector_type(4))) fv4;

// ---- K1: tile-local counting sort of edges into coarse dst-buckets ----
// (identical to round-8 known-good version)
__global__ void __launch_bounds__(NT) k_bin(const int4* __restrict__ src4,
                                            const int4* __restrict__ dst4, int E,
                                            int* __restrict__ gcur,
                                            unsigned* __restrict__ gbuf) {
    __shared__ int hist[NBUK];            // 2 KB
    __shared__ int lofs[NBUK];            // 2 KB
    __shared__ int gofs[NBUK];            // 2 KB
    __shared__ int wsum[4];
    __shared__ unsigned stage[TILE];      // 24 KB
    __shared__ unsigned short posb[TILE]; // 12 KB

    int t = threadIdx.x;
    long base = (long)blockIdx.x * TILE;
    int cnt = E - (int)base;
    if (cnt > TILE) cnt = TILE;

    for (int j = t; j < NBUK; j += NT) hist[j] = 0;
    __syncthreads();

    unsigned v[EPT];
    int bk[EPT];
    int rk[EPT];
#pragma unroll
    for (int k = 0; k < EPT / 4; k++) {
        int i4 = t + k * NT;
        if (4 * i4 < cnt) {
            int4 s = src4[base / 4 + i4];
            int4 d = dst4[base / 4 + i4];
            int ss[4] = {s.x, s.y, s.z, s.w};
            int dd[4] = {d.x, d.y, d.z, d.w};
#pragma unroll
            for (int j = 0; j < 4; j++) {
                int q = 4 * k + j;
                bk[q] = dd[j] >> BSHIFT;
                v[q] = ((unsigned)(dd[j] & BMASK) << SRCBITS) | (unsigned)ss[j];
                rk[q] = atomicAdd(&hist[bk[q]], 1);   // rank = old count
            }
        } else {
#pragma unroll
            for (int j = 0; j < 4; j++) bk[4 * k + j] = -1;
        }
    }
    __syncthreads();

    // exclusive scan over 512 bucket counts: wave shfl scan + wave-total combine
    int a0 = hist[2 * t], a1 = hist[2 * t + 1];
    int ts = a0 + a1;
    int lane = t & 63, wv = t >> 6;
    int inc = ts;
#pragma unroll
    for (int d = 1; d < 64; d <<= 1) {
        int y = __shfl_up(inc, d);
        if (lane >= d) inc += y;
    }
    if (lane == 63) wsum[wv] = inc;
    __syncthreads();
    int wpre = 0;
#pragma unroll
    for (int w = 0; w < 4; w++) wpre += (w < wv) ? wsum[w] : 0;
    int excl = wpre + inc - ts;

    lofs[2 * t] = excl;
    lofs[2 * t + 1] = excl + a0;
    if (a0 > 0) gofs[2 * t] = atomicAdd(&gcur[2 * t], a0) - excl;
    if (a1 > 0) gofs[2 * t + 1] = atomicAdd(&gcur[2 * t + 1], a1) - (excl + a0);
    __syncthreads();

#pragma unroll
    for (int k = 0; k < EPT; k++) {
        if (bk[k] >= 0) {
            int slot = lofs[bk[k]] + rk[k];
            stage[slot] = v[k];
            posb[slot] = (unsigned short)bk[k];
        }
    }
    __syncthreads();

#pragma unroll
    for (int k = 0; k < EPT; k++) {
        int idx = t + k * NT;
        if (idx < cnt) {
            int b2 = posb[idx];
            gbuf[(size_t)b2 * CAP + idx + gofs[b2]] = stage[idx];
        }
    }
}

// ---- K2: per-bucket counting sort (round-8 structure) + fused transform,
//          now emitting split fp16 tables hpA (ch 0-3) / hpB (ch 4-7). ----
__global__ void __launch_bounds__(NT) k_sort(unsigned* __restrict__ gbuf,
                                             const int* __restrict__ gcur,
                                             const float* __restrict__ x,
                                             const float* __restrict__ W,
                                             float* __restrict__ dinv,
                                             int* __restrict__ offs,
                                             int* __restrict__ cnts,
                                             uint2* __restrict__ hpA,
                                             uint2* __restrict__ hpB, int N) {
    __shared__ unsigned sorted[CAP];   // 44 KB
    __shared__ int hist[BNODES];       // 4 KB (counts, then start offsets)
    __shared__ int wsum[4];
    __shared__ float Ws[OUT_CH * IN_CH]; // 0.5 KB

    int b = blockIdx.x, t = threadIdx.x;
    int cnt = gcur[b];
    unsigned* p = gbuf + (size_t)b * CAP;

    if (t < OUT_CH * IN_CH) Ws[t] = W[t];
    for (int j = t; j < BNODES; j += NT) hist[j] = 0;
    __syncthreads();

    // pass 1: vectorized load into registers + histogram of local dst (rank)
    unsigned v[RPT];
    int rk[RPT];
#pragma unroll
    for (int k4 = 0; k4 < RPT / 4; k4++) {
        int idx = 4 * t + k4 * 4 * NT;       // always < CAP, in-bounds read
        uint4 vv = *(const uint4*)(p + idx);
        unsigned vs[4] = {vv.x, vv.y, vv.z, vv.w};
#pragma unroll
        for (int j = 0; j < 4; j++) {
            int k = 4 * k4 + j;
            if (idx + j < cnt) {
                v[k] = vs[j];
                rk[k] = atomicAdd(&hist[v[k] >> SRCBITS], 1);
            }
        }
    }
    __syncthreads();

    // exclusive scan over 1024 counts: wave shfl scan + wave-total combine
    int h0 = hist[4 * t], h1 = hist[4 * t + 1], h2 = hist[4 * t + 2], h3 = hist[4 * t + 3];
    int ts = h0 + h1 + h2 + h3;
    int lane = t & 63, wv = t >> 6;
    int inc = ts;
#pragma unroll
    for (int d = 1; d < 64; d <<= 1) {
        int y = __shfl_up(inc, d);
        if (lane >= d) inc += y;
    }
    if (lane == 63) wsum[wv] = inc;
    __syncthreads();
    int wpre = 0;
#pragma unroll
    for (int w = 0; w < 4; w++) wpre += (w < wv) ? wsum[w] : 0;
    int e0 = wpre + inc - ts;
    int e1 = e0 + h0, e2 = e1 + h1, e3 = e2 + h2;
    hist[4 * t] = e0; hist[4 * t + 1] = e1; hist[4 * t + 2] = e2; hist[4 * t + 3] = e3;

    // emit offs / cnts / dinv (4 consecutive nodes per thread, 16 B aligned)
    int nb = b << BSHIFT;
    int n0 = nb + 4 * t;
    int gofs2 = b * CAP;
    float di0 = rsqrtf(1.0f + (float)h0), di1 = rsqrtf(1.0f + (float)h1);
    float di2 = rsqrtf(1.0f + (float)h2), di3 = rsqrtf(1.0f + (float)h3);
    if (n0 + 3 < N) {
        *(int4*)(offs + n0) = make_int4(gofs2 + e0, gofs2 + e1, gofs2 + e2, gofs2 + e3);
        *(int4*)(cnts + n0) = make_int4(h0, h1, h2, h3);
        *(float4*)(dinv + n0) = make_float4(di0, di1, di2, di3);
    } else {
#pragma unroll
        for (int k = 0; k < 4; k++) {
            int n = n0 + k;
            if (n < N) {
                int hv = (k == 0) ? h0 : (k == 1) ? h1 : (k == 2) ? h2 : h3;
                int ev = (k == 0) ? e0 : (k == 1) ? e1 : (k == 2) ? e2 : e3;
                float dv = (k == 0) ? di0 : (k == 1) ? di1 : (k == 2) ? di2 : di3;
                offs[n] = gofs2 + ev;
                cnts[n] = hv;
                dinv[n] = dv;
            }
        }
    }
    __syncthreads();

    // pass 2: scatter from registers into LDS sorted[] (no atomics)
#pragma unroll
    for (int k4 = 0; k4 < RPT / 4; k4++) {
#pragma unroll
        for (int j = 0; j < 4; j++) {
            int k = 4 * k4 + j;
            int idx = 4 * t + k4 * 4 * NT + j;
            if (idx < cnt) {
                int slot = hist[v[k] >> SRCBITS] + rk[k];
                sorted[slot] = v[k] & SRCMASK;
            }
        }
    }
    __syncthreads();

    // pass 3: vectorized coalesced write-back
    int full = cnt & ~3;
    for (int i = 4 * t; i < full; i += 4 * NT) {
        uint4 sv = *(const uint4*)&sorted[i];
        *(uint4*)(p + i) = sv;
    }
    for (int i = full + t; i < cnt; i += NT) p[i] = sorted[i];

    // fused transform -> split tables (dinv already in registers)
    float dis[4] = {di0, di1, di2, di3};
#pragma unroll
    for (int k = 0; k < 4; k++) {
        int n = n0 + k;
        if (n >= N) break;
        const float4* xp = (const float4*)(x + (size_t)n * IN_CH);
        float4 a0 = xp[0], a1 = xp[1], a2 = xp[2], a3 = xp[3];
        float xi[IN_CH] = {a0.x, a0.y, a0.z, a0.w, a1.x, a1.y, a1.z, a1.w,
                           a2.x, a2.y, a2.z, a2.w, a3.x, a3.y, a3.z, a3.w};
        float di = dis[k];
        float h[OUT_CH];
#pragma unroll
        for (int o = 0; o < OUT_CH; o++) {
            float s = 0.0f;
#pragma unroll
            for (int i = 0; i < IN_CH; i++) s += xi[i] * Ws[o * IN_CH + i];
            h[o] = s * di;
        }
        union { uint2 u; __half2 h2[2]; } pa, pb;
        pa.h2[0] = __float22half2_rn(make_float2(h[0], h[1]));
        pa.h2[1] = __float22half2_rn(make_float2(h[2], h[3]));
        pb.h2[0] = __float22half2_rn(make_float2(h[4], h[5]));
        pb.h2[1] = __float22half2_rn(make_float2(h[6], h[7]));
        hpA[n] = pa.u;
        hpB[n] = pb.u;
    }
}

// ---- K3: pull gather, XCD-split tables. Blocks with (blockIdx>>2)&1==0 land
// on XCDs 0-3 (round-robin dispatch heuristic) and read only hpA (4 MB ->
// L2-resident per XCD); the rest read only hpB. 2 lanes per node per half. ----
__device__ __forceinline__ void acc_add4(float* a, uint2 g) {
    union { uint2 u; __half2 h2[2]; } pk;
    pk.u = g;
    float2 f0 = __half22float2(pk.h2[0]);
    float2 f1 = __half22float2(pk.h2[1]);
    a[0] += f0.x; a[1] += f0.y; a[2] += f1.x; a[3] += f1.y;
}

__global__ void __launch_bounds__(NT) k_gather(const unsigned* __restrict__ gbuf,
                                               const int* __restrict__ offs,
                                               const int* __restrict__ cnts,
                                               const uint2* __restrict__ hpA,
                                               const uint2* __restrict__ hpB,
                                               const float* __restrict__ dinv,
                                               const float* __restrict__ bias,
                                               float* __restrict__ out, int N) {
    int b = blockIdx.x;
    int half = (b >> 2) & 1;                      // XCD b&7: 0-3 -> A, 4-7 -> B
    int logical = (b >> 3) * 4 + (b & 3);
    long ltid = (long)logical * NT + threadIdx.x;
    int n = (int)(ltid >> 1);
    if (n >= N) return;
    int q = (int)ltid & 1;

    const uint2* __restrict__ hp = half ? hpB : hpA;

    int beg = offs[n];
    int end = beg + cnts[n];

    float a[4] = {0, 0, 0, 0};
    if (q == 0) acc_add4(a, hp[n]);               // self-loop term

    // this lane handles edges beg+q, beg+q+2, ... (4-deep pipeline)
    int e = beg + q;
    for (; e + 6 < end; e += 8) {
        unsigned s0 = __builtin_nontemporal_load(gbuf + e);
        unsigned s1 = __builtin_nontemporal_load(gbuf + e + 2);
        unsigned s2 = __builtin_nontemporal_load(gbuf + e + 4);
        unsigned s3 = __builtin_nontemporal_load(gbuf + e + 6);
        uint2 g0 = hp[s0];
        uint2 g1 = hp[s1];
        uint2 g2 = hp[s2];
        uint2 g3 = hp[s3];
        acc_add4(a, g0); acc_add4(a, g1); acc_add4(a, g2); acc_add4(a, g3);
    }
    for (; e < end; e += 2) {
        uint2 g0 = hp[__builtin_nontemporal_load(gbuf + e)];
        acc_add4(a, g0);
    }

    // pair reduction: lanes 2j, 2j+1 hold the same node
#pragma unroll
    for (int c = 0; c < 4; c++) a[c] += __shfl_xor(a[c], 1);

    if (q == 0) {
        float di = dinv[n];
        fv4 o;
        o[0] = a[0] * di + bias[4 * half + 0];
        o[1] = a[1] * di + bias[4 * half + 1];
        o[2] = a[2] * di + bias[4 * half + 2];
        o[3] = a[3] * di + bias[4 * half + 3];
        __builtin_nontemporal_store(o, (fv4*)(out + (size_t)n * OUT_CH + 4 * half));
    }
}

extern "C" void kernel_launch(void* const* d_in, const int* in_sizes, int n_in,
                              void* d_out, int out_size, void* d_ws, size_t ws_size,
                              hipStream_t stream) {
    const float* x  = (const float*)d_in[0];
    const int*   ei = (const int*)d_in[1];   // [2, E] int32
    const float* W  = (const float*)d_in[2];
    const float* b  = (const float*)d_in[3];
    float* out = (float*)d_out;

    const int N = in_sizes[0] / IN_CH;
    const int E = in_sizes[1] / 2;
    const int* src = ei;
    const int* dst = ei + E;

    const int nbuckets = (N + BNODES - 1) >> BSHIFT;   // 489

    // workspace: gcur[NBUK] | dinv[N] | hpA[N] (8 B) | hpB[N] (8 B) |
    //            gbuf[NBUK*CAP] | offs[N] | cnts[N]   (~37 MB)
    int*      gcur = (int*)d_ws;
    float*    dinv = (float*)(gcur + NBUK);
    uint2*    hpA  = (uint2*)(dinv + N);
    uint2*    hpB  = hpA + N;
    unsigned* gbuf = (unsigned*)(hpB + N);
    int*      offs = (int*)(gbuf + (size_t)NBUK * CAP);
    int*      cnts = offs + N;

    const int tiles = (E + TILE - 1) / TILE;           // 814

    // gather grid: 2 halves x 2 lanes/node; logical blocks per half:
    const int bph = (2 * N + NT - 1) / NT;             // 3907
    int gblocks = ((2 * bph + 7) / 8) * 8;             // multiple of 8

    (void)hipMemsetAsync(gcur, 0, NBUK * sizeof(int), stream);
    k_bin<<<tiles, NT, 0, stream>>>((const int4*)src, (const int4*)dst, E, gcur, gbuf);
    k_sort<<<nbuckets, NT, 0, stream>>>(gbuf, gcur, x, W, dinv, offs, cnts, hpA, hpB, N);
    k_gather<<<gblocks, NT, 0, stream>>>(gbuf, offs, cnts, hpA, hpB, dinv, b, out, N);
}

// Round 12
// 215.129 us; speedup vs baseline: 1.1932x; 1.1932x over previous
//
#include <hip/hip_runtime.h>
#include <hip/hip_fp16.h>

#define IN_CH 16
#define OUT_CH 8

#define NT 256          // threads per block
#define EPT 24          // edges per thread in k_bin
#define TILE (NT*EPT)   // 6144 edges per tile
#define NBUK 512        // allocated buckets (489 active for N=500k)
#define BSHIFT 10       // bucket = dst >> 10  (1024 nodes per bucket)
#define BNODES 1024
#define BMASK 1023
#define SRCBITS 19      // src < 2^19 (N=500000 < 524288)
#define SRCMASK 0x7FFFF
#define CAP 11264       // slots per bucket (mean 10240, +10 sigma); CAP/NT == 44
#define RPT 44          // register-cached edges per thread in k_sortgather

typedef float __attribute__((ext_vector_type(4))) fv4;

// ---- K1: tile-local counting sort of edges into coarse dst-buckets ----
// (round-8 known-good version, unchanged)
__global__ void __launch_bounds__(NT) k_bin(const int4* __restrict__ src4,
                                            const int4* __restrict__ dst4, int E,
                                            int* __restrict__ gcur,
                                            unsigned* __restrict__ gbuf) {
    __shared__ int hist[NBUK];            // 2 KB
    __shared__ int lofs[NBUK];            // 2 KB
    __shared__ int gofs[NBUK];            // 2 KB
    __shared__ int wsum[4];
    __shared__ unsigned stage[TILE];      // 24 KB
    __shared__ unsigned short posb[TILE]; // 12 KB

    int t = threadIdx.x;
    long base = (long)blockIdx.x * TILE;
    int cnt = E - (int)base;
    if (cnt > TILE) cnt = TILE;

    for (int j = t; j < NBUK; j += NT) hist[j] = 0;
    __syncthreads();

    unsigned v[EPT];
    int bk[EPT];
    int rk[EPT];
#pragma unroll
    for (int k = 0; k < EPT / 4; k++) {
        int i4 = t + k * NT;
        if (4 * i4 < cnt) {
            int4 s = src4[base / 4 + i4];
            int4 d = dst4[base / 4 + i4];
            int ss[4] = {s.x, s.y, s.z, s.w};
            int dd[4] = {d.x, d.y, d.z, d.w};
#pragma unroll
            for (int j = 0; j < 4; j++) {
                int q = 4 * k + j;
                bk[q] = dd[j] >> BSHIFT;
                v[q] = ((unsigned)(dd[j] & BMASK) << SRCBITS) | (unsigned)ss[j];
                rk[q] = atomicAdd(&hist[bk[q]], 1);   // rank = old count
            }
        } else {
#pragma unroll
            for (int j = 0; j < 4; j++) bk[4 * k + j] = -1;
        }
    }
    __syncthreads();

    // exclusive scan over 512 bucket counts: wave shfl scan + wave-total combine
    int a0 = hist[2 * t], a1 = hist[2 * t + 1];
    int ts = a0 + a1;
    int lane = t & 63, wv = t >> 6;
    int inc = ts;
#pragma unroll
    for (int d = 1; d < 64; d <<= 1) {
        int y = __shfl_up(inc, d);
        if (lane >= d) inc += y;
    }
    if (lane == 63) wsum[wv] = inc;
    __syncthreads();
    int wpre = 0;
#pragma unroll
    for (int w = 0; w < 4; w++) wpre += (w < wv) ? wsum[w] : 0;
    int excl = wpre + inc - ts;

    lofs[2 * t] = excl;
    lofs[2 * t + 1] = excl + a0;
    if (a0 > 0) gofs[2 * t] = atomicAdd(&gcur[2 * t], a0) - excl;
    if (a1 > 0) gofs[2 * t + 1] = atomicAdd(&gcur[2 * t + 1], a1) - (excl + a0);
    __syncthreads();

#pragma unroll
    for (int k = 0; k < EPT; k++) {
        if (bk[k] >= 0) {
            int slot = lofs[bk[k]] + rk[k];
            stage[slot] = v[k];
            posb[slot] = (unsigned short)bk[k];
        }
    }
    __syncthreads();

#pragma unroll
    for (int k = 0; k < EPT; k++) {
        int idx = t + k * NT;
        if (idx < cnt) {
            int b2 = posb[idx];
            gbuf[(size_t)b2 * CAP + idx + gofs[b2]] = stage[idx];
        }
    }
}

// ---- K2: per-bucket degree histogram + fused transform ----
// One block per bucket. Produces hp16 = fp16(dinv * x@W^T) so the fused
// sort+gather kernel has no cross-block dependency (no grid sync needed).
__global__ void __launch_bounds__(NT) k_degtrans(const unsigned* __restrict__ gbuf,
                                                 const int* __restrict__ gcur,
                                                 const float* __restrict__ x,
                                                 const float* __restrict__ W,
                                                 uint4* __restrict__ hp16, int N) {
    __shared__ int hist[BNODES];         // 4 KB
    __shared__ float Ws[OUT_CH * IN_CH]; // 0.5 KB

    int b = blockIdx.x, t = threadIdx.x;
    int cnt = gcur[b];
    const unsigned* p = gbuf + (size_t)b * CAP;

    if (t < OUT_CH * IN_CH) Ws[t] = W[t];
    for (int j = t; j < BNODES; j += NT) hist[j] = 0;
    __syncthreads();

    // histogram of local dst (vectorized reads; in-bounds since CAP%1024==0)
    int n4 = (cnt + 3) >> 2;
    for (int i4 = t; i4 < n4; i4 += NT) {
        uint4 vv = *(const uint4*)(p + 4 * i4);
        unsigned vs[4] = {vv.x, vv.y, vv.z, vv.w};
#pragma unroll
        for (int j = 0; j < 4; j++)
            if (4 * i4 + j < cnt) atomicAdd(&hist[vs[j] >> SRCBITS], 1);
    }
    __syncthreads();

    // transform own 4 nodes
    int n0 = (b << BSHIFT) + 4 * t;
#pragma unroll
    for (int k = 0; k < 4; k++) {
        int n = n0 + k;
        if (n >= N) break;
        float di = rsqrtf(1.0f + (float)hist[4 * t + k]);
        const float4* xp = (const float4*)(x + (size_t)n * IN_CH);
        float4 a0 = xp[0], a1 = xp[1], a2 = xp[2], a3 = xp[3];
        float xi[IN_CH] = {a0.x, a0.y, a0.z, a0.w, a1.x, a1.y, a1.z, a1.w,
                           a2.x, a2.y, a2.z, a2.w, a3.x, a3.y, a3.z, a3.w};
        float h[OUT_CH];
#pragma unroll
        for (int o = 0; o < OUT_CH; o++) {
            float s = 0.0f;
#pragma unroll
            for (int i = 0; i < IN_CH; i++) s += xi[i] * Ws[o * IN_CH + i];
            h[o] = s * di;
        }
        union { uint4 u; __half2 h2[4]; } pk;
        pk.h2[0] = __float22half2_rn(make_float2(h[0], h[1]));
        pk.h2[1] = __float22half2_rn(make_float2(h[2], h[3]));
        pk.h2[2] = __float22half2_rn(make_float2(h[4], h[5]));
        pk.h2[3] = __float22half2_rn(make_float2(h[6], h[7]));
        hp16[n] = pk.u;
    }
}

// ---- K3: fused per-bucket sort (LDS only, no write-back) + pull gather ----
__device__ __forceinline__ void acc_add(float* a, uint4 g) {
    union { uint4 u; __half2 h2[4]; } pk;
    pk.u = g;
    float2 f0 = __half22float2(pk.h2[0]);
    float2 f1 = __half22float2(pk.h2[1]);
    float2 f2 = __half22float2(pk.h2[2]);
    float2 f3 = __half22float2(pk.h2[3]);
    a[0] += f0.x; a[1] += f0.y; a[2] += f1.x; a[3] += f1.y;
    a[4] += f2.x; a[5] += f2.y; a[6] += f3.x; a[7] += f3.y;
}

__global__ void __launch_bounds__(NT) k_sortgather(const unsigned* __restrict__ gbuf,
                                                   const int* __restrict__ gcur,
                                                   const uint4* __restrict__ hp16,
                                                   const float* __restrict__ bias,
                                                   float* __restrict__ out, int N) {
    __shared__ unsigned sorted[CAP];   // 44 KB
    __shared__ int hist[BNODES];       // 4 KB (counts, then start offsets)
    __shared__ int wsum[4];

    int b = blockIdx.x, t = threadIdx.x;
    int cnt = gcur[b];
    const unsigned* p = gbuf + (size_t)b * CAP;

    for (int j = t; j < BNODES; j += NT) hist[j] = 0;
    __syncthreads();

    // pass 1: vectorized load into registers + histogram of local dst (rank)
    unsigned v[RPT];
    int rk[RPT];
#pragma unroll
    for (int k4 = 0; k4 < RPT / 4; k4++) {
        int idx = 4 * t + k4 * 4 * NT;       // always < CAP, in-bounds read
        uint4 vv = *(const uint4*)(p + idx);
        unsigned vs[4] = {vv.x, vv.y, vv.z, vv.w};
#pragma unroll
        for (int j = 0; j < 4; j++) {
            int k = 4 * k4 + j;
            if (idx + j < cnt) {
                v[k] = vs[j];
                rk[k] = atomicAdd(&hist[v[k] >> SRCBITS], 1);
            }
        }
    }
    __syncthreads();

    // exclusive scan over 1024 counts: wave shfl scan + wave-total combine
    int h0 = hist[4 * t], h1 = hist[4 * t + 1], h2 = hist[4 * t + 2], h3 = hist[4 * t + 3];
    int ts = h0 + h1 + h2 + h3;
    int lane = t & 63, wv = t >> 6;
    int inc = ts;
#pragma unroll
    for (int d = 1; d < 64; d <<= 1) {
        int y = __shfl_up(inc, d);
        if (lane >= d) inc += y;
    }
    if (lane == 63) wsum[wv] = inc;
    __syncthreads();
    int wpre = 0;
#pragma unroll
    for (int w = 0; w < 4; w++) wpre += (w < wv) ? wsum[w] : 0;
    int e0 = wpre + inc - ts;
    int e1 = e0 + h0, e2 = e1 + h1, e3 = e2 + h2;
    // reuse hist as the start-offset table (each thread touches only its 4 slots)
    hist[4 * t] = e0; hist[4 * t + 1] = e1; hist[4 * t + 2] = e2; hist[4 * t + 3] = e3;
    __syncthreads();

    // pass 2: scatter from registers into LDS sorted[] (src only; no atomics)
#pragma unroll
    for (int k4 = 0; k4 < RPT / 4; k4++) {
#pragma unroll
        for (int j = 0; j < 4; j++) {
            int k = 4 * k4 + j;
            int idx = 4 * t + k4 * 4 * NT + j;
            if (idx < cnt) {
                int slot = hist[v[k] >> SRCBITS] + rk[k];
                sorted[slot] = v[k] & SRCMASK;
            }
        }
    }
    __syncthreads();

    // gather phase: this thread's 4 nodes; edge lists read from LDS,
    // hp16 rows gathered from global (single 8 MB table)
    int n0 = (b << BSHIFT) + 4 * t;
    int eS[4] = {e0, e1, e2, e3};
    int hS[4] = {h0, h1, h2, h3};

    float bb[OUT_CH];
#pragma unroll
    for (int o = 0; o < OUT_CH; o++) bb[o] = bias[o];

#pragma unroll
    for (int k = 0; k < 4; k++) {
        int n = n0 + k;
        if (n >= N) break;

        float a[OUT_CH];
        acc_add((float*)a, hp16[n]);               // self-loop term (init)
#pragma unroll
        for (int o = 0; o < OUT_CH; o++) a[o] = a[o];   // (acc initialized below)
        // re-init properly: acc_add added to garbage; do explicit init instead
        {
            union { uint4 u; __half2 h2[4]; } pk;
            pk.u = hp16[n];
            float2 f0 = __half22float2(pk.h2[0]);
            float2 f1 = __half22float2(pk.h2[1]);
            float2 f2 = __half22float2(pk.h2[2]);
            float2 f3 = __half22float2(pk.h2[3]);
            a[0] = f0.x; a[1] = f0.y; a[2] = f1.x; a[3] = f1.y;
            a[4] = f2.x; a[5] = f2.y; a[6] = f3.x; a[7] = f3.y;
        }

        int e = eS[k], end = eS[k] + hS[k];
        for (; e + 3 < end; e += 4) {
            unsigned s0 = sorted[e], s1 = sorted[e + 1];
            unsigned s2 = sorted[e + 2], s3 = sorted[e + 3];
            uint4 g0 = hp16[s0];
            uint4 g1 = hp16[s1];
            uint4 g2 = hp16[s2];
            uint4 g3 = hp16[s3];
            acc_add(a, g0); acc_add(a, g1); acc_add(a, g2); acc_add(a, g3);
        }
        for (; e < end; e++) {
            uint4 g0 = hp16[sorted[e]];
            acc_add(a, g0);
        }

        float di = rsqrtf(1.0f + (float)hS[k]);
        fv4 o0, o1;
#pragma unroll
        for (int j = 0; j < 4; j++) {
            o0[j] = a[j] * di + bb[j];
            o1[j] = a[4 + j] * di + bb[4 + j];
        }
        __builtin_nontemporal_store(o0, (fv4*)(out + (size_t)n * OUT_CH));
        __builtin_nontemporal_store(o1, (fv4*)(out + (size_t)n * OUT_CH) + 1);
    }
}

extern "C" void kernel_launch(void* const* d_in, const int* in_sizes, int n_in,
                              void* d_out, int out_size, void* d_ws, size_t ws_size,
                              hipStream_t stream) {
    const float* x  = (const float*)d_in[0];
    const int*   ei = (const int*)d_in[1];   // [2, E] int32
    const float* W  = (const float*)d_in[2];
    const float* b  = (const float*)d_in[3];
    float* out = (float*)d_out;

    const int N = in_sizes[0] / IN_CH;
    const int E = in_sizes[1] / 2;
    const int* src = ei;
    const int* dst = ei + E;

    const int nbuckets = (N + BNODES - 1) >> BSHIFT;   // 489

    // workspace: gcur[NBUK] | hp16[N] (16 B) | gbuf[NBUK*CAP]  (~31 MB)
    int*      gcur = (int*)d_ws;
    uint4*    hp16 = (uint4*)(gcur + NBUK);
    unsigned* gbuf = (unsigned*)(hp16 + N);

    const int tiles = (E + TILE - 1) / TILE;           // 814

    (void)hipMemsetAsync(gcur, 0, NBUK * sizeof(int), stream);
    k_bin<<<tiles, NT, 0, stream>>>((const int4*)src, (const int4*)dst, E, gcur, gbuf);
    k_degtrans<<<nbuckets, NT, 0, stream>>>(gbuf, gcur, x, W, hp16, N);
    k_sortgather<<<nbuckets, NT, 0, stream>>>(gbuf, gcur, hp16, b, out, N);
}